// Round 1
// baseline (167.309 us; speedup 1.0000x reference)
//
#include <hip/hip_runtime.h>
#include <cstdint>
#include <cstddef>

#define W_ 512
#define H_ 512
#define N_ 8
#define C_ 19
#define HW_ (W_*H_)
#define NPIX_ (N_*HW_)

// ---------------- K1: channel max/argmax -> sml, pred(u8), pred(float out) ----
__global__ __launch_bounds__(256) void k_argmax_sml(
    const float* __restrict__ x, const float* __restrict__ means,
    const float* __restrict__ stdv, float* __restrict__ sml,
    uint8_t* __restrict__ pred8, float* __restrict__ predf)
{
    int q = blockIdx.x * blockDim.x + threadIdx.x;   // quad-pixel index
    if (q >= NPIX_/4) return;
    int pix = q * 4;
    int n = pix / HW_;
    int p = pix - n * HW_;
    const float* base = x + (size_t)n * C_ * HW_ + p;
    float4 mv = *(const float4*)base;
    int ix = 0, iy = 0, iz = 0, iw = 0;
    #pragma unroll
    for (int c = 1; c < C_; ++c) {
        float4 v = *(const float4*)(base + (size_t)c * HW_);
        if (v.x > mv.x) { mv.x = v.x; ix = c; }
        if (v.y > mv.y) { mv.y = v.y; iy = c; }
        if (v.z > mv.z) { mv.z = v.z; iz = c; }
        if (v.w > mv.w) { mv.w = v.w; iw = c; }
    }
    float4 s;
    s.x = (mv.x - means[ix]) / stdv[ix];
    s.y = (mv.y - means[iy]) / stdv[iy];
    s.z = (mv.z - means[iz]) / stdv[iz];
    s.w = (mv.w - means[iw]) / stdv[iw];
    *(float4*)(sml + pix) = s;
    uchar4 pc; pc.x = (uint8_t)ix; pc.y = (uint8_t)iy; pc.z = (uint8_t)iz; pc.w = (uint8_t)iw;
    *(uchar4*)(pred8 + pix) = pc;
    float4 pf; pf.x = (float)ix; pf.y = (float)iy; pf.z = (float)iz; pf.w = (float)iw;
    *(float4*)(predf + pix) = pf;
}

// ---------------- K2: boundary = (cross-dilate(pred) != full-erode(pred)) ----
__global__ __launch_bounds__(256) void k_boundary(
    const uint8_t* __restrict__ pred8, uint8_t* __restrict__ bnd)
{
    int pix = blockIdx.x * blockDim.x + threadIdx.x;
    if (pix >= NPIX_) return;
    int n = pix / HW_;
    int p = pix - n * HW_;
    int h = p / W_, w = p - h * W_;
    const uint8_t* pr = pred8 + (size_t)n * HW_;
    int c = pr[p];
    int mx = c, mn = c;
    // cross (5-point) max; out-of-bounds = -inf (ignored)
    if (h > 0)     { int v = pr[p - W_]; mx = mx > v ? mx : v; }
    if (h < H_-1)  { int v = pr[p + W_]; mx = mx > v ? mx : v; }
    if (w > 0)     { int v = pr[p - 1];  mx = mx > v ? mx : v; }
    if (w < W_-1)  { int v = pr[p + 1];  mx = mx > v ? mx : v; }
    // full 3x3 min; out-of-bounds = +inf (ignored)
    #pragma unroll
    for (int dy = -1; dy <= 1; ++dy) {
        int hh = h + dy; if (hh < 0 || hh >= H_) continue;
        #pragma unroll
        for (int dx = -1; dx <= 1; ++dx) {
            int ww = w + dx; if (ww < 0 || ww >= W_) continue;
            int v = pr[hh*W_ + ww];
            mn = mn < v ? mn : v;
        }
    }
    bnd[pix] = (mx != mn) ? (uint8_t)1 : (uint8_t)0;
}

// ---------------- K3: L1 distance transform (radius 3), dist>3 -> 4 ----------
// expand_boundaries(b, r) == (dist <= r); nb_mask == (dist > r)
__global__ __launch_bounds__(256) void k_dist(
    const uint8_t* __restrict__ bnd, uint8_t* __restrict__ dist)
{
    int pix = blockIdx.x * blockDim.x + threadIdx.x;
    if (pix >= NPIX_) return;
    int n = pix / HW_;
    int p = pix - n * HW_;
    int h = p / W_, w = p - h * W_;
    const uint8_t* bb = bnd + (size_t)n * HW_;
    int d = 4;
    #pragma unroll
    for (int dy = -3; dy <= 3; ++dy) {
        int hh = h + dy; if (hh < 0 || hh >= H_) continue;
        int ady = dy < 0 ? -dy : dy;
        int rx = 3 - ady;
        for (int dx = -rx; dx <= rx; ++dx) {
            int ww = w + dx; if (ww < 0 || ww >= W_) continue;
            if (bb[hh*W_ + ww]) {
                int dd = ady + (dx < 0 ? -dx : dx);
                d = d < dd ? d : dd;
            }
        }
    }
    dist[pix] = (uint8_t)d;
}

// ---------------- K4: one smoothing iteration for radius r -------------------
__global__ __launch_bounds__(256) void k_smooth(
    const float* __restrict__ sin_, const uint8_t* __restrict__ dist,
    float* __restrict__ sout, int r)
{
    int pix = blockIdx.x * blockDim.x + threadIdx.x;
    if (pix >= NPIX_) return;
    int n = pix / HW_;
    int p = pix - n * HW_;
    int h = p / W_, w = p - h * W_;
    const uint8_t* dd = dist + (size_t)n * HW_;
    const float*   ss = sin_ + (size_t)n * HW_;
    float cen = ss[p];
    if (dd[p] > r) { sout[pix] = cen; return; }   // non-boundary: keep
    float s = 0.f; int cnt = 0;
    #pragma unroll
    for (int dy = -1; dy <= 1; ++dy) {
        int hh = h + dy; if (hh < 0 || hh >= H_) continue;
        #pragma unroll
        for (int dx = -1; dx <= 1; ++dx) {
            int ww = w + dx; if (ww < 0 || ww >= W_) continue;
            if (dd[hh*W_ + ww] > r) { s += ss[hh*W_ + ww]; cnt++; }
        }
    }
    sout[pix] = cnt ? s / (float)cnt : cen;
}

// ---------------- K5: 7x7 gaussian conv, zero-padded SAME --------------------
__global__ __launch_bounds__(256) void k_conv7(
    const float* __restrict__ sml, const float* __restrict__ gk,
    float* __restrict__ out)
{
    __shared__ float kk[49];
    int tid = threadIdx.x;
    if (tid < 49) kk[tid] = gk[tid];
    __syncthreads();
    int tx = tid & 63, ty = tid >> 6;
    int w = blockIdx.x * 64 + tx;
    int h = blockIdx.y * 4 + ty;
    int n = blockIdx.z;
    const float* ss = sml + (size_t)n * HW_;
    float acc = 0.f;
    #pragma unroll
    for (int i = 0; i < 7; ++i) {
        int hh = h + i - 3; if (hh < 0 || hh >= H_) continue;
        #pragma unroll
        for (int j = 0; j < 7; ++j) {
            int ww = w + j - 3; if (ww < 0 || ww >= W_) continue;
            acc += kk[i*7+j] * ss[hh*W_ + ww];
        }
    }
    out[(size_t)n * HW_ + h * W_ + w] = acc;
}

extern "C" void kernel_launch(void* const* d_in, const int* in_sizes, int n_in,
                              void* d_out, int out_size, void* d_ws, size_t ws_size,
                              hipStream_t stream)
{
    const float* x     = (const float*)d_in[0];
    const float* means = (const float*)d_in[1];
    const float* stdv  = (const float*)d_in[2];
    const float* gk    = (const float*)d_in[3];
    float* out_sml  = (float*)d_out;             // first 2,097,152 floats
    float* out_pred = (float*)d_out + NPIX_;     // next  2,097,152 floats

    char* ws = (char*)d_ws;
    float*   smlA  = (float*)(ws);                       //  8,388,608 B
    float*   smlB  = (float*)(ws + 8388608);             //  8,388,608 B
    uint8_t* pred8 = (uint8_t*)(ws + 16777216);          //  2,097,152 B
    uint8_t* bnd   = (uint8_t*)(ws + 18874368);          //  2,097,152 B
    uint8_t* dist  = (uint8_t*)(ws + 20971520);          //  2,097,152 B

    dim3 blk(256);
    k_argmax_sml<<<NPIX_/4/256, blk, 0, stream>>>(x, means, stdv, smlA, pred8, out_pred);
    k_boundary<<<NPIX_/256, blk, 0, stream>>>(pred8, bnd);
    k_dist    <<<NPIX_/256, blk, 0, stream>>>(bnd, dist);
    // BOUNDARY_PER_ITERATION = [3, 2, 1, 0]; nb_mask = (dist > r)
    k_smooth<<<NPIX_/256, blk, 0, stream>>>(smlA, dist, smlB, 3);
    k_smooth<<<NPIX_/256, blk, 0, stream>>>(smlB, dist, smlA, 2);
    k_smooth<<<NPIX_/256, blk, 0, stream>>>(smlA, dist, smlB, 1);
    k_smooth<<<NPIX_/256, blk, 0, stream>>>(smlB, dist, smlA, 0);
    dim3 cgrd(W_/64, H_/4, N_);
    k_conv7<<<cgrd, blk, 0, stream>>>(smlA, gk, out_sml);
}

// Round 2
// 91.588 us; speedup vs baseline: 1.8268x; 1.8268x over previous
//
#include <hip/hip_runtime.h>
#include <cstdint>
#include <cstddef>

#define W_ 512
#define H_ 512
#define N_ 8
#define C_ 19
#define HW_ (W_*H_)
#define NPIX_ (N_*HW_)

// fused tile geometry (all offsets relative to tile origin)
#define TS  32      // output tile side
#define SP  54      // pred region side   (halo 11)
#define SB  52      // bnd region side    (halo 10)
#define SD  46      // dist region side   (halo 7)
#define SS  46      // sml region side    (halo 7)
#define SSP 48      // padded row stride for float LDS tiles

// ---------------- K1: channel max/argmax -> sml, pred(u8), pred(float out) ----
__global__ __launch_bounds__(256) void k_argmax_sml(
    const float* __restrict__ x, const float* __restrict__ means,
    const float* __restrict__ stdv, float* __restrict__ sml,
    uint8_t* __restrict__ pred8, float* __restrict__ predf)
{
    int q = blockIdx.x * blockDim.x + threadIdx.x;   // quad-pixel index
    if (q >= NPIX_/4) return;
    int pix = q * 4;
    int n = pix / HW_;
    int p = pix - n * HW_;
    const float* base = x + (size_t)n * C_ * HW_ + p;
    float4 mv = *(const float4*)base;
    int ix = 0, iy = 0, iz = 0, iw = 0;
    #pragma unroll
    for (int c = 1; c < C_; ++c) {
        float4 v = *(const float4*)(base + (size_t)c * HW_);
        if (v.x > mv.x) { mv.x = v.x; ix = c; }
        if (v.y > mv.y) { mv.y = v.y; iy = c; }
        if (v.z > mv.z) { mv.z = v.z; iz = c; }
        if (v.w > mv.w) { mv.w = v.w; iw = c; }
    }
    float4 s;
    s.x = (mv.x - means[ix]) / stdv[ix];
    s.y = (mv.y - means[iy]) / stdv[iy];
    s.z = (mv.z - means[iz]) / stdv[iz];
    s.w = (mv.w - means[iw]) / stdv[iw];
    *(float4*)(sml + pix) = s;
    uchar4 pc; pc.x = (uint8_t)ix; pc.y = (uint8_t)iy; pc.z = (uint8_t)iz; pc.w = (uint8_t)iw;
    *(uchar4*)(pred8 + pix) = pc;
    float4 pf; pf.x = (float)ix; pf.y = (float)iy; pf.z = (float)iz; pf.w = (float)iw;
    *(float4*)(predf + pix) = pf;
}

// ---------------- K2: fused boundary + dist + 4x smooth + 7x7 conv -----------
__global__ __launch_bounds__(256) void k_fused(
    const float* __restrict__ sml_g, const uint8_t* __restrict__ pred8,
    const float* __restrict__ gk, float* __restrict__ out)
{
    __shared__ uint8_t predT[SP*SP];
    __shared__ uint8_t bndT[SB*SB];
    __shared__ uint8_t distT[SD*SD];
    __shared__ float   smlA[SS*SSP];
    __shared__ float   smlB[SS*SSP];
    __shared__ float   kk[49];

    const int tid = threadIdx.x;
    const int tx0 = blockIdx.x * TS;
    const int ty0 = blockIdx.y * TS;
    const int n   = blockIdx.z;
    const uint8_t* pr = pred8 + (size_t)n * HW_;
    const float*   sg = sml_g + (size_t)n * HW_;

    if (tid < 49) kk[tid] = gk[tid];

    // ---- load pred, clamp-to-edge (exact for dilate/erode/dist) ----
    for (int s = tid; s < SP*SP; s += 256) {
        int ly = s / SP, lx = s - ly*SP;
        int gy = ty0 + ly - 11; gy = gy < 0 ? 0 : (gy > H_-1 ? H_-1 : gy);
        int gx = tx0 + lx - 11; gx = gx < 0 ? 0 : (gx > W_-1 ? W_-1 : gx);
        predT[s] = pr[gy*W_ + gx];
    }
    // ---- load sml halo-7 (OOB values shielded later by dist==0) ----
    for (int s = tid; s < SS*SS; s += 256) {
        int ly = s / SS, lx = s - ly*SS;
        int gy = ty0 + ly - 7; gy = gy < 0 ? 0 : (gy > H_-1 ? H_-1 : gy);
        int gx = tx0 + lx - 7; gx = gx < 0 ? 0 : (gx > W_-1 ? W_-1 : gx);
        smlA[ly*SSP + lx] = sg[gy*W_ + gx];
    }
    __syncthreads();

    // ---- boundary on 52x52: bnd(y,x) <-> pred(y+1,x+1) ----
    for (int s = tid; s < SB*SB; s += 256) {
        int ly = s / SB, lx = s - ly*SB;
        const uint8_t* p = &predT[(ly+1)*SP + (lx+1)];
        int c  = p[0];
        int up = p[-SP], dn = p[SP], lf = p[-1], rt = p[1];
        int mx = max(max(c, up), max(dn, max(lf, rt)));              // cross dilate
        int mn = min(min(min(c, up), min(dn, lf)), rt);              // full 3x3 erode
        mn = min(mn, min(min((int)p[-SP-1], (int)p[-SP+1]),
                         min((int)p[ SP-1], (int)p[ SP+1])));
        bndT[s] = (uint8_t)(mx != mn);
    }
    __syncthreads();

    // ---- L1 distance (cap 4) on 46x46; forced 0 at global-OOB ----
    for (int s = tid; s < SD*SD; s += 256) {
        int ly = s / SD, lx = s - ly*SD;
        int gy = ty0 + ly - 7, gx = tx0 + lx - 7;
        int d;
        if (gy < 0 || gy >= H_ || gx < 0 || gx >= W_) d = 0;
        else {
            d = 4;
            const uint8_t* b0 = &bndT[(ly+3)*SB + (lx+3)];
            #pragma unroll
            for (int dy = -3; dy <= 3; ++dy) {
                int ady = dy < 0 ? -dy : dy;
                int rx = 3 - ady;
                for (int dx = -rx; dx <= rx; ++dx) {
                    if (b0[dy*SB + dx]) {
                        int dd = ady + (dx < 0 ? -dx : dx);
                        d = d < dd ? d : dd;
                    }
                }
            }
        }
        distT[s] = (uint8_t)d;
    }
    __syncthreads();

    // ---- 4 smoothing passes r=3,2,1,0; pass k computes [1+k, 45-k)^2 ----
    const float* src = smlA;
    float*       dst = smlB;
    #pragma unroll
    for (int k = 0; k < 4; ++k) {
        const int r  = 3 - k;
        const int lo = 1 + k;
        const int L  = 44 - 2*k;      // region side
        for (int s = tid; s < L*L; s += 256) {
            int qy = s / L;
            int ly = qy + lo, lx = s - qy*L + lo;
            int gy = ty0 + ly - 7, gx = tx0 + lx - 7;
            float o;
            if (gy < 0 || gy >= H_ || gx < 0 || gx >= W_) o = 0.f;  // zero-pad for conv
            else {
                int   dd = distT[ly*SD + lx];
                float c  = src[ly*SSP + lx];
                if (dd > r) o = c;                                   // non-boundary: keep
                else {
                    float sum = 0.f; int cnt = 0;
                    #pragma unroll
                    for (int dy = -1; dy <= 1; ++dy) {
                        #pragma unroll
                        for (int dx = -1; dx <= 1; ++dx) {
                            if (distT[(ly+dy)*SD + (lx+dx)] > r) {   // OOB has dist=0 -> skipped
                                sum += src[(ly+dy)*SSP + (lx+dx)];
                                cnt++;
                            }
                        }
                    }
                    o = cnt ? sum / (float)cnt : c;
                }
            }
            dst[ly*SSP + lx] = o;
        }
        __syncthreads();
        const float* t = src; src = dst; dst = (float*)t;
    }
    // after 4 passes, final smoothed values live in smlA (== src)

    // ---- 7x7 gaussian conv on the 32x32 tile; input region [4,42) ----
    for (int s = tid; s < TS*TS; s += 256) {
        int oy = s >> 5, ox = s & 31;
        float acc = 0.f;
        #pragma unroll
        for (int i = 0; i < 7; ++i) {
            #pragma unroll
            for (int j = 0; j < 7; ++j) {
                acc += kk[i*7 + j] * src[(oy + i + 4)*SSP + (ox + j + 4)];
            }
        }
        out[(size_t)n * HW_ + (size_t)(ty0 + oy)*W_ + (tx0 + ox)] = acc;
    }
}

extern "C" void kernel_launch(void* const* d_in, const int* in_sizes, int n_in,
                              void* d_out, int out_size, void* d_ws, size_t ws_size,
                              hipStream_t stream)
{
    const float* x     = (const float*)d_in[0];
    const float* means = (const float*)d_in[1];
    const float* stdv  = (const float*)d_in[2];
    const float* gk    = (const float*)d_in[3];
    float* out_sml  = (float*)d_out;             // first 2,097,152 floats
    float* out_pred = (float*)d_out + NPIX_;     // next  2,097,152 floats

    char* ws = (char*)d_ws;
    float*   sml   = (float*)(ws);               //  8,388,608 B
    uint8_t* pred8 = (uint8_t*)(ws + 8388608);   //  2,097,152 B

    k_argmax_sml<<<NPIX_/4/256, 256, 0, stream>>>(x, means, stdv, sml, pred8, out_pred);
    dim3 fgrd(W_/TS, H_/TS, N_);
    k_fused<<<fgrd, 256, 0, stream>>>(sml, pred8, gk, out_sml);
}

// Round 3
// 66.864 us; speedup vs baseline: 2.5022x; 1.3698x over previous
//
#include <hip/hip_runtime.h>
#include <cstdint>
#include <cstddef>

#define W_ 512
#define H_ 512
#define N_ 8
#define C_ 19
#define HW_ (W_*H_)      // 262144 = 2^18
#define NPIX_ (N_*HW_)

#define TS  32           // output tile side
#define SD  46           // sml region side (halo 7)
#define SSP 48           // padded LDS row stride for floats
#define BR  52           // bnd-mask rows per tile (halo 10); bnd-local = dist-local + 3

typedef float   f32x4 __attribute__((ext_vector_type(4)));
typedef uint8_t u8x4  __attribute__((ext_vector_type(4)));
typedef unsigned long long u64;

// ---------------- K1: channel max/argmax -> sml, pred(u8), pred(float out) ----
__global__ __launch_bounds__(256) void k_argmax_sml(
    const float* __restrict__ x, const float* __restrict__ means,
    const float* __restrict__ stdv, float* __restrict__ sml,
    uint8_t* __restrict__ pred8, float* __restrict__ predf)
{
    int q = blockIdx.x * blockDim.x + threadIdx.x;   // quad-pixel index
    int pix = q * 4;
    int n = pix >> 18;
    int p = pix & (HW_ - 1);
    const float* base = x + (size_t)n * C_ * HW_ + p;
    f32x4 mv = __builtin_nontemporal_load((const f32x4*)base);
    int ix = 0, iy = 0, iz = 0, iw = 0;
    #pragma unroll
    for (int c = 1; c < C_; ++c) {
        f32x4 v = __builtin_nontemporal_load((const f32x4*)(base + (size_t)c * HW_));
        if (v[0] > mv[0]) { mv[0] = v[0]; ix = c; }
        if (v[1] > mv[1]) { mv[1] = v[1]; iy = c; }
        if (v[2] > mv[2]) { mv[2] = v[2]; iz = c; }
        if (v[3] > mv[3]) { mv[3] = v[3]; iw = c; }
    }
    f32x4 s;
    s[0] = (mv[0] - means[ix]) / stdv[ix];
    s[1] = (mv[1] - means[iy]) / stdv[iy];
    s[2] = (mv[2] - means[iz]) / stdv[iz];
    s[3] = (mv[3] - means[iw]) / stdv[iw];
    *(f32x4*)(sml + pix) = s;
    u8x4 pc; pc[0] = (uint8_t)ix; pc[1] = (uint8_t)iy; pc[2] = (uint8_t)iz; pc[3] = (uint8_t)iw;
    *(u8x4*)(pred8 + pix) = pc;
    f32x4 pf; pf[0] = (float)ix; pf[1] = (float)iy; pf[2] = (float)iz; pf[3] = (float)iw;
    *(f32x4*)(predf + pix) = pf;
}

// ---------------- K2: boundary bits -> packed row masks (8 u64 per row) ------
__global__ __launch_bounds__(256) void k_bnd(
    const uint8_t* __restrict__ pred8, u64* __restrict__ bndM)
{
    int gid  = blockIdx.x * 256 + threadIdx.x;
    int lane = gid & 63;
    int wave = gid >> 6;
    int w = wave & 7;
    int y = (wave >> 3) & 511;
    int n = wave >> 12;
    int xx = w * 64 + lane;
    const uint8_t* pc = pred8 + (size_t)n * HW_ + y * W_ + xx;
    int c = pc[0];
    bool u = y > 0, d = y < H_-1, l = xx > 0, r = xx < W_-1;
    int up = u ? pc[-W_] : c;
    int dn = d ? pc[ W_] : c;
    int lf = l ? pc[-1]  : c;
    int rt = r ? pc[ 1]  : c;
    int mx = max(max(c, up), max(dn, max(lf, rt)));       // cross dilate
    int mn = min(min(c, up), min(dn, min(lf, rt)));       // full 3x3 erode
    int c00 = (u && l) ? pc[-W_-1] : c;
    int c01 = (u && r) ? pc[-W_+1] : c;
    int c10 = (d && l) ? pc[ W_-1] : c;
    int c11 = (d && r) ? pc[ W_+1] : c;
    mn = min(mn, min(min(c00, c01), min(c10, c11)));
    u64 m = __ballot(mx != mn);
    if (lane == 0) bndM[((size_t)n * 512 + y) * 8 + w] = m;
}

// ---------------- K3: fused dist-masks + 4x smooth + separable 7x7 conv ------
__global__ __launch_bounds__(256) void k_fused(
    const float* __restrict__ sml_g, const u64* __restrict__ bndM,
    const float* __restrict__ gk, float* __restrict__ out)
{
    __shared__ u64 M0[BR], E1[BR], E2[BR], E3[BR], VM[BR];
    __shared__ u64 NBM[4][BR];
    __shared__ float smlA[SD*SSP], smlB[SD*SSP];
    __shared__ float htmp[38*33];
    __shared__ float g7[7];

    const int tid = threadIdx.x;
    const int tx0 = blockIdx.x * TS;
    const int ty0 = blockIdx.y * TS;
    const int n   = blockIdx.z;
    const float* sg = sml_g + (size_t)n * HW_;

    if (tid < 7) g7[tid] = gk[21 + tid] / sqrtf(gk[24]);   // kk = outer(g,g)

    // ---- load 52 bnd row-masks (window [tx0-10, tx0+42)) + validity masks ----
    if (tid < BR) {
        int i  = tid;
        int gy = ty0 + i - 10;
        int bx0 = tx0 - 10;
        u64 m = 0, vm = 0;
        if (gy >= 0 && gy < H_) {
            const u64* row = bndM + ((size_t)n * 512 + gy) * 8;
            int sft = bx0 & 63;
            int wi  = bx0 >> 6;                       // arithmetic shift: -10 -> -1
            u64 w0 = (wi >= 0) ? row[wi] : 0ULL;
            u64 w1 = (wi + 1 <= 7) ? row[wi + 1] : 0ULL;
            m = sft ? ((w0 >> sft) | (w1 << (64 - sft))) : w0;
            int lo = bx0 < 0 ? -bx0 : 0;
            int hi = (512 - bx0) < 52 ? (512 - bx0) : 52;
            if (hi > lo) vm = ((1ULL << (hi - lo)) - 1ULL) << lo;
        }
        M0[i] = m;
        VM[i] = vm;
    }
    // ---- load sml region 46x46 (clamped addr; OOB values gated by VM) ----
    for (int s = tid; s < SD*SD; s += 256) {
        int ly = s / SD, lx = s - ly * SD;
        int gy = ty0 + ly - 7; gy = gy < 0 ? 0 : (gy > H_-1 ? H_-1 : gy);
        int gx = tx0 + lx - 7; gx = gx < 0 ? 0 : (gx > W_-1 ? W_-1 : gx);
        smlA[ly*SSP + lx] = sg[gy*W_ + gx];
    }
    __syncthreads();

    // ---- cross-dilations by bit ops: E_{k+1}[y] = dx(E_k[y]) | E_k[y-1] | E_k[y+1]
    if (tid < BR) {
        u64 a = M0[tid], u = tid > 0 ? M0[tid-1] : 0, d = tid < BR-1 ? M0[tid+1] : 0;
        E1[tid] = a | (a << 1) | (a >> 1) | u | d;
    }
    __syncthreads();
    if (tid < BR) {
        u64 a = E1[tid], u = tid > 0 ? E1[tid-1] : 0, d = tid < BR-1 ? E1[tid+1] : 0;
        E2[tid] = a | (a << 1) | (a >> 1) | u | d;
    }
    __syncthreads();
    if (tid < BR) {
        u64 a = E2[tid], u = tid > 0 ? E2[tid-1] : 0, d = tid < BR-1 ? E2[tid+1] : 0;
        E3[tid] = a | (a << 1) | (a >> 1) | u | d;
    }
    __syncthreads();
    {   // NB_r = ~E_r & valid   (r = 0..3 across the 4 thread quarters)
        int r = tid >> 6, i = tid & 63;
        if (i < BR) {
            u64 e = (r == 0) ? M0[i] : (r == 1) ? E1[i] : (r == 2) ? E2[i] : E3[i];
            NBM[r][i] = ~e & VM[i];
        }
    }
    __syncthreads();

    // ---- 4 smoothing passes r=3,2,1,0; pass k computes [1+k, 45-k)^2 ----
    const float* src = smlA;
    float*       dst = smlB;
    #pragma unroll
    for (int k = 0; k < 4; ++k) {
        const int r  = 3 - k;
        const int lo = 1 + k;
        const int L  = 44 - 2*k;
        for (int s = tid; s < L*L; s += 256) {
            int qy = s / L;
            int ly = qy + lo, lx = s - qy*L + lo;
            int gy = ty0 + ly - 7, gx = tx0 + lx - 7;
            float o = 0.f;                                   // zero-pad for conv
            if (gy >= 0 && gy < H_ && gx >= 0 && gx < W_) {
                const u64* NB = NBM[r];
                int bi = ly + 3;                              // bnd-local row
                int sh = lx + 2;                              // (bnd col) - 1
                u64 fu = (NB[bi-1] >> sh) & 7ULL;
                u64 fc = (NB[bi  ] >> sh) & 7ULL;
                u64 fd = (NB[bi+1] >> sh) & 7ULL;
                float c = src[ly*SSP + lx];
                if (((fc >> 1) & 1ULL) | (u64)!(fu | fc | fd)) {
                    o = c;                                    // keep (non-bnd or cnt==0)
                } else {
                    int cnt = __popcll(fu) + __popcll(fc) + __popcll(fd);
                    float sum = 0.f;
                    const float* r0 = &src[(ly-1)*SSP + lx];
                    const float* r1 = &src[(ly  )*SSP + lx];
                    const float* r2 = &src[(ly+1)*SSP + lx];
                    if (fu & 1) sum += r0[-1];
                    if (fu & 2) sum += r0[0];
                    if (fu & 4) sum += r0[1];
                    if (fc & 1) sum += r1[-1];
                    if (fc & 4) sum += r1[1];
                    if (fd & 1) sum += r2[-1];
                    if (fd & 2) sum += r2[0];
                    if (fd & 4) sum += r2[1];
                    o = sum / (float)cnt;
                }
            }
            dst[ly*SSP + lx] = o;
        }
        __syncthreads();
        const float* t = src; src = dst; dst = (float*)t;
    }
    // final smoothed values are in `src` (== smlA), region [4,42)^2

    // ---- separable 7x7 gaussian: horizontal into htmp, then vertical ----
    for (int s = tid; s < 38*32; s += 256) {
        int hy = s >> 5, hx = s & 31;
        const float* p = &src[(hy + 4)*SSP + (hx + 7)];
        htmp[hy*33 + hx] = g7[0]*p[-3] + g7[1]*p[-2] + g7[2]*p[-1] + g7[3]*p[0]
                         + g7[4]*p[ 1] + g7[5]*p[ 2] + g7[6]*p[ 3];
    }
    __syncthreads();
    for (int s = tid; s < TS*TS; s += 256) {
        int oy = s >> 5, ox = s & 31;
        const float* p = &htmp[oy*33 + ox];
        float a = g7[0]*p[0]   + g7[1]*p[33]  + g7[2]*p[66]  + g7[3]*p[99]
                + g7[4]*p[132] + g7[5]*p[165] + g7[6]*p[198];
        out[(size_t)n*HW_ + (size_t)(ty0 + oy)*W_ + (tx0 + ox)] = a;
    }
}

extern "C" void kernel_launch(void* const* d_in, const int* in_sizes, int n_in,
                              void* d_out, int out_size, void* d_ws, size_t ws_size,
                              hipStream_t stream)
{
    const float* x     = (const float*)d_in[0];
    const float* means = (const float*)d_in[1];
    const float* stdv  = (const float*)d_in[2];
    const float* gk    = (const float*)d_in[3];
    float* out_sml  = (float*)d_out;
    float* out_pred = (float*)d_out + NPIX_;

    char* ws = (char*)d_ws;
    float*   sml   = (float*)(ws);                 // 8,388,608 B
    uint8_t* pred8 = (uint8_t*)(ws + 8388608);     // 2,097,152 B
    u64*     bndM  = (u64*)(ws + 10485760);        //   262,144 B (8 imgs x 512 rows x 8 words)

    k_argmax_sml<<<NPIX_/4/256, 256, 0, stream>>>(x, means, stdv, sml, pred8, out_pred);
    k_bnd<<<NPIX_/256, 256, 0, stream>>>(pred8, bndM);
    dim3 fgrd(W_/TS, H_/TS, N_);
    k_fused<<<fgrd, 256, 0, stream>>>(sml, bndM, gk, out_sml);
}

// Round 5
// 55.877 us; speedup vs baseline: 2.9943x; 1.1966x over previous
//
#include <hip/hip_runtime.h>
#include <cstdint>
#include <cstddef>

#define W_ 512
#define H_ 512
#define N_ 8
#define C_ 19
#define HW_ (W_*H_)      // 262144 = 2^18
#define NPIX_ (N_*HW_)

#define TS  32           // output tile side
#define SR  46           // sml region rows (halo 7)
#define SC  48           // sml region cols: [tx0-8, tx0+40), 16B-aligned
#define BR  52           // bnd-mask rows per tile: [ty0-10, ty0+42)

typedef float   f32x4 __attribute__((ext_vector_type(4)));
typedef uint8_t u8x4  __attribute__((ext_vector_type(4)));
typedef unsigned long long u64;

// Coordinate maps inside k_fused (tile origin tx0,ty0):
//   smlA[ly][lx] : gy = ty0+ly-7 (ly in [0,46)),  gx = tx0+lx-8 (lx in [0,48))
//   bnd mask row i <-> gy = ty0+i-10 ; bit b <-> gx = tx0+b-10
//   pixel (ly,lx) -> mask row bi = ly+3, center bit = lx+2, window shift = lx+1
//   conv output (oy,ox) <-> (ly,lx) = (oy+7, ox+8)

// ---------------- K1: channel max/argmax -> sml, pred(u8), pred(float out) ----
__global__ __launch_bounds__(256) void k_argmax_sml(
    const float* __restrict__ x, const float* __restrict__ means,
    const float* __restrict__ stdv, float* __restrict__ sml,
    uint8_t* __restrict__ pred8, float* __restrict__ predf)
{
    int q = blockIdx.x * blockDim.x + threadIdx.x;   // quad-pixel index
    int pix = q * 4;
    int n = pix >> 18;
    int p = pix & (HW_ - 1);
    const float* base = x + (size_t)n * C_ * HW_ + p;
    f32x4 mv = __builtin_nontemporal_load((const f32x4*)base);
    int ix = 0, iy = 0, iz = 0, iw = 0;
    #pragma unroll
    for (int c = 1; c < C_; ++c) {
        f32x4 v = __builtin_nontemporal_load((const f32x4*)(base + (size_t)c * HW_));
        if (v[0] > mv[0]) { mv[0] = v[0]; ix = c; }
        if (v[1] > mv[1]) { mv[1] = v[1]; iy = c; }
        if (v[2] > mv[2]) { mv[2] = v[2]; iz = c; }
        if (v[3] > mv[3]) { mv[3] = v[3]; iw = c; }
    }
    f32x4 s;
    s[0] = (mv[0] - means[ix]) / stdv[ix];
    s[1] = (mv[1] - means[iy]) / stdv[iy];
    s[2] = (mv[2] - means[iz]) / stdv[iz];
    s[3] = (mv[3] - means[iw]) / stdv[iw];
    *(f32x4*)(sml + pix) = s;
    u8x4 pc; pc[0] = (uint8_t)ix; pc[1] = (uint8_t)iy; pc[2] = (uint8_t)iz; pc[3] = (uint8_t)iw;
    *(u8x4*)(pred8 + pix) = pc;
    f32x4 pf; pf[0] = (float)ix; pf[1] = (float)iy; pf[2] = (float)iz; pf[3] = (float)iw;
    __builtin_nontemporal_store(pf, (f32x4*)(predf + pix));
}

// ---------------- K2: boundary bits -> packed row masks (8 u64 per row) ------
__global__ __launch_bounds__(256) void k_bnd(
    const uint8_t* __restrict__ pred8, u64* __restrict__ bndM)
{
    int gid  = blockIdx.x * 256 + threadIdx.x;
    int lane = gid & 63;
    int wave = gid >> 6;
    int w = wave & 7;
    int y = (wave >> 3) & 511;
    int n = wave >> 12;
    int xx = w * 64 + lane;
    const uint8_t* pc = pred8 + (size_t)n * HW_ + y * W_ + xx;
    int c = pc[0];
    bool u = y > 0, d = y < H_-1, l = xx > 0, r = xx < W_-1;
    int up = u ? pc[-W_] : c;
    int dn = d ? pc[ W_] : c;
    int lf = l ? pc[-1]  : c;
    int rt = r ? pc[ 1]  : c;
    int mx = max(max(c, up), max(dn, max(lf, rt)));       // cross dilate
    int mn = min(min(c, up), min(dn, min(lf, rt)));       // full 3x3 erode
    int c00 = (u && l) ? pc[-W_-1] : c;
    int c01 = (u && r) ? pc[-W_+1] : c;
    int c10 = (d && l) ? pc[ W_-1] : c;
    int c11 = (d && r) ? pc[ W_+1] : c;
    mn = min(mn, min(min(c00, c01), min(c10, c11)));
    u64 m = __ballot(mx != mn);
    if (lane == 0) bndM[((size_t)n * 512 + y) * 8 + w] = m;
}

// ---------------- K3: fused masks + (skippable) smooth + separable conv ------
__global__ __launch_bounds__(256) void k_fused(
    const float* __restrict__ sml_g, const u64* __restrict__ bndM,
    const float* __restrict__ gk, float* __restrict__ out)
{
    __shared__ float smlA[SR*SC];
    __shared__ float smlB[SR*SC];           // active-staging; later aliased as htmp
    __shared__ u64 M0[BR], E1[BR], E2[BR], E3[BR], VM[BR];
    __shared__ u64 NBM[4][BR];
    __shared__ float g7[7];
    __shared__ int tACT;

    const int tid = threadIdx.x;
    const int bx = blockIdx.x, by = blockIdx.y, n = blockIdx.z;
    const int tx0 = bx * TS, ty0 = by * TS;
    const float* sg = sml_g + (size_t)n * HW_;

    if (tid == 0) tACT = 0;
    if (tid < 7) g7[tid] = gk[21 + tid] / sqrtf(gk[24]);   // kk = outer(g,g)

    // ---- load 52 bnd row-masks (window [tx0-10, tx0+42)) + validity masks ----
    if (tid < BR) {
        int gy = ty0 + tid - 10;
        int bx0 = tx0 - 10;
        u64 m = 0, vm = 0;
        if (gy >= 0 && gy < H_) {
            const u64* row = bndM + ((size_t)n * 512 + gy) * 8;
            int sft = bx0 & 63;
            int wi  = bx0 >> 6;                           // arithmetic: -10 -> -1
            u64 w0 = (wi >= 0) ? row[wi] : 0ULL;
            u64 w1 = (wi + 1 <= 7) ? row[wi + 1] : 0ULL;
            m = sft ? ((w0 >> sft) | (w1 << (64 - sft))) : w0;
            int lo = bx0 < 0 ? -bx0 : 0;
            int hi = (512 - bx0) < BR ? (512 - bx0) : BR;
            if (hi > lo) vm = ((1ULL << (hi - lo)) - 1ULL) << lo;
        }
        M0[tid] = m;
        VM[tid] = vm;
    }

    // ---- load sml region 46x48; OOB -> 0 (zero-pad for conv & masked sums) ----
    if (bx > 0 && bx < (W_/TS - 1)) {
        // interior-x: cols [tx0-8, tx0+40) all in-image, 16B-aligned float4s
        for (int s = tid; s < SR * (SC/4); s += 256) {
            int ly = s / (SC/4), j = s - ly * (SC/4);
            int gy = ty0 + ly - 7;
            f32x4 v = {0.f, 0.f, 0.f, 0.f};
            if ((unsigned)gy < (unsigned)H_)
                v = *(const f32x4*)(sg + (size_t)gy * W_ + (tx0 - 8) + j * 4);
            *(f32x4*)&smlA[ly * SC + j * 4] = v;
        }
    } else {
        for (int s = tid; s < SR * SC; s += 256) {
            int ly = s / SC, lx = s - ly * SC;
            int gy = ty0 + ly - 7, gx = tx0 + lx - 8;
            float v = 0.f;
            if ((unsigned)gy < (unsigned)H_ && (unsigned)gx < (unsigned)W_)
                v = sg[(size_t)gy * W_ + gx];
            smlA[ly * SC + lx] = v;
        }
    }
    __syncthreads();

    // ---- cross-dilations: E_{k+1}[y] = dx(E_k[y]) | E_k[y-1] | E_k[y+1] ----
    if (tid < BR) {
        u64 a = M0[tid], u = tid > 0 ? M0[tid-1] : 0, d = tid < BR-1 ? M0[tid+1] : 0;
        E1[tid] = a | (a << 1) | (a >> 1) | u | d;
    }
    __syncthreads();
    if (tid < BR) {
        u64 a = E1[tid], u = tid > 0 ? E1[tid-1] : 0, d = tid < BR-1 ? E1[tid+1] : 0;
        E2[tid] = a | (a << 1) | (a >> 1) | u | d;
    }
    __syncthreads();
    if (tid < BR) {
        u64 a = E2[tid], u = tid > 0 ? E2[tid-1] : 0, d = tid < BR-1 ? E2[tid+1] : 0;
        E3[tid] = a | (a << 1) | (a >> 1) | u | d;
    }
    __syncthreads();
    {   // NB_r = ~E_r & valid   (r = 0..3 across the 4 thread quarters)
        int r = tid >> 6, i = tid & 63;
        if (i < BR) {
            u64 e = (r == 0) ? M0[i] : (r == 1) ? E1[i] : (r == 2) ? E2[i] : E3[i];
            NBM[r][i] = ~e & VM[i];
        }
    }
    __syncthreads();

    // ---- active detection: px can change in some pass only if 3x3 window ∩ NB0 ≠ ∅
    u64 actRow = 0;
    if (tid < SR) {
        int bi = tid + 3;                                  // mask row for sml row tid
        u64 U = NBM[0][bi-1] | NBM[0][bi] | NBM[0][bi+1];
        u64 A = (U >> 1) | (U >> 2) | (U >> 3);            // bit lx <- bits lx+1..lx+3
        // restrict to in-image columns: gx = tx0+lx-8 in [0,512)
        int lo = tx0 == 0 ? 8 : 0;
        int hi = tx0 == (W_-TS) ? 40 : SC;
        u64 CV = (hi - lo >= 64) ? ~0ULL : (((1ULL << (hi - lo)) - 1ULL) << lo);
        actRow = A & CV;
        int gy = ty0 + tid - 7;
        if ((unsigned)gy >= (unsigned)H_) actRow = 0;
        if (actRow) tACT = 1;                              // benign race (same value)
    }
    __syncthreads();

    // ---- 4 smoothing passes r=3,2,1,0 — executed only where actives exist ----
    if (tACT) {                                            // block-uniform branch
        #pragma unroll
        for (int k = 0; k < 4; ++k) {
            const int r = 3 - k;
            const u64 colmask = ((1ULL << (44 - 2*k)) - 1ULL) << (2 + k); // lx in [2+k,46-k)
            u64 mwork = 0;
            if (tid >= 1 + k && tid < 45 - k && tid < SR)
                mwork = actRow & colmask;
            u64 mm = mwork;
            while (mm) {
                int lx = __ffsll(mm) - 1; mm &= mm - 1;
                int bi = tid + 3, sh = lx + 1;
                u64 fu = (NBM[r][bi-1] >> sh) & 7ULL;
                u64 fc = (NBM[r][bi  ] >> sh) & 7ULL;
                u64 fd = (NBM[r][bi+1] >> sh) & 7ULL;
                float c = smlA[tid*SC + lx];
                float o;
                if (((fc >> 1) & 1ULL) || !(fu | fc | fd)) {
                    o = c;                                  // non-bnd center or cnt==0
                } else {
                    int cnt = __popcll(fu) + __popcll(fc) + __popcll(fd);
                    float sum = 0.f;
                    const float* r0 = &smlA[(tid-1)*SC + lx];
                    const float* r1 = &smlA[(tid  )*SC + lx];
                    const float* r2 = &smlA[(tid+1)*SC + lx];
                    if (fu & 1) sum += r0[-1];
                    if (fu & 2) sum += r0[0];
                    if (fu & 4) sum += r0[1];
                    if (fc & 1) sum += r1[-1];
                    if (fc & 4) sum += r1[1];
                    if (fd & 1) sum += r2[-1];
                    if (fd & 2) sum += r2[0];
                    if (fd & 4) sum += r2[1];
                    o = sum / (float)cnt;
                }
                smlB[tid*SC + lx] = o;
            }
            __syncthreads();
            mm = mwork;
            while (mm) {
                int lx = __ffsll(mm) - 1; mm &= mm - 1;
                smlA[tid*SC + lx] = smlB[tid*SC + lx];
            }
            __syncthreads();
        }
    }

    // ---- separable 7x7 gaussian: horizontal into smlB(htmp), then vertical ----
    // htmp[hy][hx] (stride 33): row ly = hy+4, center col lx = hx+8, taps lx-3..lx+3
    float* htmp = smlB;
    for (int s = tid; s < 38 * 32; s += 256) {
        int hy = s >> 5, hx = s & 31;
        const float* p = &smlA[(hy + 4)*SC + (hx + 5)];
        htmp[hy*33 + hx] = g7[0]*p[0] + g7[1]*p[1] + g7[2]*p[2] + g7[3]*p[3]
                         + g7[4]*p[4] + g7[5]*p[5] + g7[6]*p[6];
    }
    __syncthreads();
    for (int s = tid; s < TS*TS; s += 256) {
        int oy = s >> 5, ox = s & 31;
        const float* p = &htmp[oy*33 + ox];
        float a = g7[0]*p[0]   + g7[1]*p[33]  + g7[2]*p[66]  + g7[3]*p[99]
                + g7[4]*p[132] + g7[5]*p[165] + g7[6]*p[198];
        out[(size_t)n*HW_ + (size_t)(ty0 + oy)*W_ + (tx0 + ox)] = a;
    }
}

extern "C" void kernel_launch(void* const* d_in, const int* in_sizes, int n_in,
                              void* d_out, int out_size, void* d_ws, size_t ws_size,
                              hipStream_t stream)
{
    const float* x     = (const float*)d_in[0];
    const float* means = (const float*)d_in[1];
    const float* stdv  = (const float*)d_in[2];
    const float* gk    = (const float*)d_in[3];
    float* out_sml  = (float*)d_out;
    float* out_pred = (float*)d_out + NPIX_;

    char* ws = (char*)d_ws;
    float*   sml   = (float*)(ws);                 // 8,388,608 B
    uint8_t* pred8 = (uint8_t*)(ws + 8388608);     // 2,097,152 B
    u64*     bndM  = (u64*)(ws + 10485760);        //   262,144 B

    k_argmax_sml<<<NPIX_/4/256, 256, 0, stream>>>(x, means, stdv, sml, pred8, out_pred);
    k_bnd<<<NPIX_/256, 256, 0, stream>>>(pred8, bndM);
    dim3 fgrd(W_/TS, H_/TS, N_);
    k_fused<<<fgrd, 256, 0, stream>>>(sml, bndM, gk, out_sml);
}